// Round 4
// baseline (28.961 us; speedup 1.0000x reference)
//
#include <hip/hip_runtime.h>

// LIF neuron scan: v' = v*0.5 + x + r; s = (v'>0); v = s ? 0 : v'
// T=100 sequential steps, B*N = 131072 independent chains.
// Irreducible traffic: read 105 MB + write 52 MB = 157 MB.
//
// R3: float4 per thread (16 B/lane loads = 1 KB per wave-instruction, the
// coalescing sweet spot). 32768 lanes -> 256 blocks x 128 = 2 waves/CU.
// Trend so far: 4B/8w = 30.3 us, 8B/4w = 28.1 us; testing 16B/2w.
// unroll 4 -> 8 x 1 KB loads in flight per wave = 16 KB/CU outstanding,
// above the ~9 KB/CU needed for 6.3 TB/s at ~900 cy HBM latency.

#define TAU 0.5f

__global__ __launch_bounds__(128) void lif_scan_kernel(
    const float4* __restrict__ inp,
    const float4* __restrict__ rec,
    float4* __restrict__ out,
    int n4,   // float4 lanes per timestep (B*N/4) = 32768
    int T)    // 100
{
    const int i = blockIdx.x * blockDim.x + threadIdx.x;
    if (i >= n4) return;

    float v0 = 0.0f, v1 = 0.0f, v2 = 0.0f, v3 = 0.0f;

    #pragma unroll 4
    for (int t = 0; t < T; ++t) {
        const size_t off = (size_t)t * (size_t)n4 + (size_t)i;
        const float4 x = inp[off];
        const float4 r = rec[off];

        // v*0.5 is exact (pow2), so fma contraction cannot change the
        // rounded result vs numpy's (v*0.5 + x) + r -> spike test exact.
        v0 = v0 * TAU + x.x + r.x;
        v1 = v1 * TAU + x.y + r.y;
        v2 = v2 * TAU + x.z + r.z;
        v3 = v3 * TAU + x.w + r.w;

        float4 s;
        s.x = (v0 > 0.0f) ? 1.0f : 0.0f;
        s.y = (v1 > 0.0f) ? 1.0f : 0.0f;
        s.z = (v2 > 0.0f) ? 1.0f : 0.0f;
        s.w = (v3 > 0.0f) ? 1.0f : 0.0f;

        v0 = (v0 > 0.0f) ? 0.0f : v0;
        v1 = (v1 > 0.0f) ? 0.0f : v1;
        v2 = (v2 > 0.0f) ? 0.0f : v2;
        v3 = (v3 > 0.0f) ? 0.0f : v3;

        out[off] = s;
    }
}

extern "C" void kernel_launch(void* const* d_in, const int* in_sizes, int n_in,
                              void* d_out, int out_size, void* d_ws, size_t ws_size,
                              hipStream_t stream) {
    const float* inp = (const float*)d_in[0];
    const float* rec = (const float*)d_in[1];
    float* out = (float*)d_out;

    const int T = 100;
    const int per_t = in_sizes[0] / T;   // B*N = 131072
    const int n4 = per_t / 4;            // 32768 float4 lanes

    const int block = 128;
    const int grid = (n4 + block - 1) / block;   // 256 blocks -> 1 per CU

    lif_scan_kernel<<<grid, block, 0, stream>>>(
        (const float4*)inp, (const float4*)rec, (float4*)out, n4, T);
}